// Round 8
// baseline (269.978 us; speedup 1.0000x reference)
//
#include <hip/hip_runtime.h>

typedef __attribute__((ext_vector_type(4))) float f32x4;
typedef __attribute__((ext_vector_type(8))) short s16x8;
typedef __attribute__((ext_vector_type(4))) short s16x4;
typedef __attribute__((ext_vector_type(4))) unsigned u32x4;
typedef __attribute__((ext_vector_type(2))) unsigned u32x2;

__device__ __forceinline__ short f2bf(float f) {          // RNE (weights/scalars)
    unsigned u = __builtin_bit_cast(unsigned, f);
    u += 0x7fffu + ((u >> 16) & 1u);
    return (short)(u >> 16);
}
__device__ __forceinline__ unsigned cvt_pk_bf16(float a, float b) {  // lo=a, hi=b (RNE)
    unsigned r;
    asm("v_cvt_pk_bf16_f32 %0, %1, %2" : "=v"(r) : "v"(a), "v"(b));
    return r;
}
__device__ __forceinline__ s16x4 pack4(float v0, float v1, float v2, float v3) {
    u32x2 p;
    p[0] = cvt_pk_bf16(v0, v1);
    p[1] = cvt_pk_bf16(v2, v3);
    return __builtin_bit_cast(s16x4, p);
}

// ---------------------------------------------------------------------------
// Weight prep: transpose to [n][k] bf16. W1T zero-padded to K=32 for MFMA L1.
// ---------------------------------------------------------------------------
__global__ void k_prep(const float* __restrict__ W1,
                       const float* __restrict__ W2, const float* __restrict__ W3,
                       const float* __restrict__ W4,
                       const float* __restrict__ Wc1, const float* __restrict__ Wc2,
                       const float* __restrict__ Wc3, const float* __restrict__ Wc4,
                       short* __restrict__ W1T,
                       short* __restrict__ W2T, short* __restrict__ W3T,
                       float* __restrict__ W4T,
                       short* __restrict__ Wc1T, short* __restrict__ Wc2T,
                       short* __restrict__ Wc3T, short* __restrict__ Wc4T)
{
    int tid = blockIdx.x * 256 + threadIdx.x;   // 65536 total
    if (tid < 4096) {   // W1T: [n<128][k<32], only k<4 nonzero
        int n = tid >> 5, k = tid & 31;
        W1T[tid] = (k < 4) ? f2bf(W1[k * 128 + n]) : (short)0;
    }
    if (tid < 16384) {  // W2T/W3T: [n<128][k<128]
        int n = tid >> 7, k = tid & 127;
        W2T[tid] = f2bf(W2[k * 128 + n]);
        W3T[tid] = f2bf(W3[k * 128 + n]);
    }
    if (tid < 256) {    // W4T: [s<2][k<128] fp32
        int s = tid >> 7, k = tid & 127;
        W4T[tid] = W4[k * 2 + s];
    }
    if (tid < 8192) {   // Wc1T: [n<128][c<64]
        int n = tid >> 6, c = tid & 63;
        Wc1T[tid] = f2bf(Wc1[c * 128 + n]);
    }
    if (tid < 32768) {  // Wc2T: [n<256][k<128]
        int n = tid >> 7, k = tid & 127;
        Wc2T[tid] = f2bf(Wc2[k * 256 + n]);
    }
    if (tid < 65536) {  // Wc3T: [n<256][k<256]
        int n = tid >> 8, k = tid & 255;
        Wc3T[tid] = f2bf(Wc3[k * 255 + k + n]);   // k*256+n, written to avoid typo
    }
    if (tid < 8192) {   // Wc4T: [n<32][k<256]
        int n = tid >> 8, k = tid & 255;
        Wc4T[tid] = f2bf(Wc4[k * 32 + n]);
    }
}

// ---------------------------------------------------------------------------
// Phase-1: 64 edge-rows per block. ALL FOUR layers matmul-shaped; L1 runs as
// zero-padded K=32 MFMA from a 1KB feature table (1 global load/thread).
// ---------------------------------------------------------------------------
__global__ __launch_bounds__(256, 4)
void k_phase1(const float* __restrict__ x,
              const float* __restrict__ b1, const short* __restrict__ W1T,
              const short* __restrict__ W2T, const float* __restrict__ b2,
              const short* __restrict__ W3T, const float* __restrict__ b3,
              const float* __restrict__ W4T, const float* __restrict__ b4,
              short* __restrict__ outb, float* __restrict__ diagpart)
{
    __shared__ short hA[64 * 128];            // 16 KB, rows swizzled ^((row&7)<<4)
    __shared__ short hB[64 * 128];            // 16 KB
    __shared__ float red[4][4][16][2];        // 2 KB cross-wave L4 partials
    __shared__ float feat[64][4];             // 1 KB fp32 feature table
    const int t = threadIdx.x;
    const int lane = t & 63;
    const int w = t >> 6;
    const int lr = lane & 15;
    const int hi = lane >> 4;
    const int b = blockIdx.x;
    const int bc = b / 63;                    // block-uniform
    const int r  = b - bc * 63;               // block-uniform
    const int n0 = w * 32;                    // wave owns 32 output features

    // ---- stage features: thread (row kk = t&63, feature q = t>>6) ----
    {
        int kk = t & 63, q = t >> 6;
        int jj = (kk + r + 1) & 63;
        const float* xb = x + bc * 4096;
        float v;
        if (q == 0)      v = xb[kk * 65];
        else if (q == 1) v = xb[kk * 64 + jj];
        else if (q == 2) v = xb[jj * 64 + kk];
        else             v = xb[jj * 65];
        feat[kk][q] = v;
    }

    // ---- preload weight fragments (issued early; compiler may sink) ----
    s16x8 aw1[2], aw2[4][2], aw3[4][2];
#pragma unroll
    for (int nf = 0; nf < 2; ++nf)
        aw1[nf] = *(const s16x8*)(W1T + (n0 + nf * 16 + lr) * 32 + hi * 8);
#pragma unroll
    for (int ks = 0; ks < 4; ++ks)
#pragma unroll
        for (int nf = 0; nf < 2; ++nf) {
            aw2[ks][nf] = *(const s16x8*)(W2T + (n0 + nf * 16 + lr) * 128 + ks * 32 + hi * 8);
            aw3[ks][nf] = *(const s16x8*)(W3T + (n0 + nf * 16 + lr) * 128 + ks * 32 + hi * 8);
        }
    __syncthreads();

    // ---- L1 (MFMA, K=4 zero-padded to 32): D[n][m] ----
    f32x4 acc1[4][2] = {};
#pragma unroll
    for (int mf = 0; mf < 4; ++mf) {
        u32x4 bw = {0u, 0u, 0u, 0u};
        if (hi == 0) {
            f32x4 fv = *(const f32x4*)(&feat[mf * 16 + lr][0]);
            bw[0] = cvt_pk_bf16(fv[0], fv[1]);
            bw[1] = cvt_pk_bf16(fv[2], fv[3]);
        }
        s16x8 bf = __builtin_bit_cast(s16x8, bw);
#pragma unroll
        for (int nf = 0; nf < 2; ++nf)
            acc1[mf][nf] = __builtin_amdgcn_mfma_f32_16x16x32_bf16(aw1[nf], bf, acc1[mf][nf], 0, 0, 0);
    }
    {   // epilogue: bias+relu -> bf16 hA
        f32x4 bv[2];
#pragma unroll
        for (int nf = 0; nf < 2; ++nf)
            bv[nf] = *(const f32x4*)(b1 + n0 + nf * 16 + 4 * hi);
#pragma unroll
        for (int mf = 0; mf < 4; ++mf) {
            int m = mf * 16 + lr;
#pragma unroll
            for (int nf = 0; nf < 2; ++nf) {
                s16x4 pk = pack4(fmaxf(acc1[mf][nf][0] + bv[nf][0], 0.f),
                                 fmaxf(acc1[mf][nf][1] + bv[nf][1], 0.f),
                                 fmaxf(acc1[mf][nf][2] + bv[nf][2], 0.f),
                                 fmaxf(acc1[mf][nf][3] + bv[nf][3], 0.f));
                int off = (m * 256 + (n0 + nf * 16 + 4 * hi) * 2) ^ ((m & 7) << 4);
                *(s16x4*)((char*)hA + off) = pk;
            }
        }
    }
    __syncthreads();

    // ---- L2 (MFMA, swapped: D[n][m]) ----
    f32x4 acc[4][2] = {};
#pragma unroll
    for (int ks = 0; ks < 4; ++ks) {
        const int kb = ks * 32 + hi * 8;
        s16x8 bh[4];
#pragma unroll
        for (int mf = 0; mf < 4; ++mf) {
            int off = ((mf * 16 + lr) * 256 + kb * 2) ^ ((lr & 7) << 4);
            bh[mf] = *(const s16x8*)((const char*)hA + off);
        }
#pragma unroll
        for (int mf = 0; mf < 4; ++mf)
#pragma unroll
            for (int nf = 0; nf < 2; ++nf)
                acc[mf][nf] = __builtin_amdgcn_mfma_f32_16x16x32_bf16(aw2[ks][nf], bh[mf], acc[mf][nf], 0, 0, 0);
    }
    {   // epilogue -> hB
        f32x4 bv[2];
#pragma unroll
        for (int nf = 0; nf < 2; ++nf)
            bv[nf] = *(const f32x4*)(b2 + n0 + nf * 16 + 4 * hi);
#pragma unroll
        for (int mf = 0; mf < 4; ++mf) {
            int m = mf * 16 + lr;
#pragma unroll
            for (int nf = 0; nf < 2; ++nf) {
                s16x4 pk = pack4(fmaxf(acc[mf][nf][0] + bv[nf][0], 0.f),
                                 fmaxf(acc[mf][nf][1] + bv[nf][1], 0.f),
                                 fmaxf(acc[mf][nf][2] + bv[nf][2], 0.f),
                                 fmaxf(acc[mf][nf][3] + bv[nf][3], 0.f));
                int off = (m * 256 + (n0 + nf * 16 + 4 * hi) * 2) ^ ((m & 7) << 4);
                *(s16x4*)((char*)hB + off) = pk;
            }
        }
    }
    __syncthreads();

    // ---- L3 (MFMA) + L4 fused in-register ----
    f32x4 acc3[4][2] = {};
#pragma unroll
    for (int ks = 0; ks < 4; ++ks) {
        const int kb = ks * 32 + hi * 8;
        s16x8 bh[4];
#pragma unroll
        for (int mf = 0; mf < 4; ++mf) {
            int off = ((mf * 16 + lr) * 256 + kb * 2) ^ ((lr & 7) << 4);
            bh[mf] = *(const s16x8*)((const char*)hB + off);
        }
#pragma unroll
        for (int mf = 0; mf < 4; ++mf)
#pragma unroll
            for (int nf = 0; nf < 2; ++nf)
                acc3[mf][nf] = __builtin_amdgcn_mfma_f32_16x16x32_bf16(aw3[ks][nf], bh[mf], acc3[mf][nf], 0, 0, 0);
    }
    {
        f32x4 bv[2], w40[2], w41[2];
#pragma unroll
        for (int nf = 0; nf < 2; ++nf) {
            bv[nf]  = *(const f32x4*)(b3 + n0 + nf * 16 + 4 * hi);
            w40[nf] = *(const f32x4*)(W4T + n0 + nf * 16 + 4 * hi);
            w41[nf] = *(const f32x4*)(W4T + 128 + n0 + nf * 16 + 4 * hi);
        }
#pragma unroll
        for (int mf = 0; mf < 4; ++mf) {
            float s0 = 0.f, s1 = 0.f;
#pragma unroll
            for (int nf = 0; nf < 2; ++nf)
#pragma unroll
                for (int q = 0; q < 4; ++q) {
                    float h = fmaxf(acc3[mf][nf][q] + bv[nf][q], 0.f);
                    s0 = fmaf(h, w40[nf][q], s0);
                    s1 = fmaf(h, w41[nf][q], s1);
                }
            s0 += __shfl_xor(s0, 16, 64); s0 += __shfl_xor(s0, 32, 64);
            s1 += __shfl_xor(s1, 16, 64); s1 += __shfl_xor(s1, 32, 64);
            if (hi == 0) { red[w][mf][lr][0] = s0; red[w][mf][lr][1] = s1; }
        }
    }
    __syncthreads();
    if (t < 128) {
        int k = t & 63, s = t >> 6;
        int mf = k >> 4, lr2 = k & 15;
        float v = red[0][mf][lr2][s] + red[1][mf][lr2][s]
                + red[2][mf][lr2][s] + red[3][mf][lr2][s] + b4[s];
        if (s) {
            int jj = (k + r + 1) & 63;
            outb[bc * 4096 + k * 64 + jj] = f2bf(v);    // off-diagonal scatter (bf16)
        } else {
            diagpart[b * 64 + k] = v;                   // h0 for diag mean (fp32)
        }
    }
}

// ---------------------------------------------------------------------------
// Diag: out[bc][k][k] = mean_r h0[bc][r][k]; coalesced rows, LDS reduce.
// ---------------------------------------------------------------------------
__global__ void k_diag(const float* __restrict__ diagpart, short* __restrict__ outb)
{
    __shared__ float rds[256];
    const int t = threadIdx.x, bcq = blockIdx.x;
    const int kx = t & 63, q = t >> 6;
    const float* p = diagpart + bcq * 4032 + kx;
    int r0 = q * 16, r1 = (r0 + 16 < 63) ? r0 + 16 : 63;
    float s = 0.f;
    for (int rr = r0; rr < r1; ++rr) s += p[rr * 64];
    rds[t] = s;
    __syncthreads();
    if (t < 64) {
        float v = (rds[t] + rds[t + 64] + rds[t + 128] + rds[t + 192]) * (1.0f / 63.0f);
        outb[bcq * 4096 + t * 65] = f2bf(v);
    }
}

// ---------------------------------------------------------------------------
// One inner layer of the fused channel MLP: [32 rows][K] bf16 (LDS, swizzled)
// -> [32 rows][N] bf16 (LDS, swizzled). 4 waves split N.
// ---------------------------------------------------------------------------
template<int K, int N, bool RELU>
__device__ __forceinline__ void chan_layer(const short* src, const short* __restrict__ WT,
                                           const float* __restrict__ bias, short* dst,
                                           int w, int lr, int hi)
{
    constexpr int NF = N / 64;
    constexpr int KS = K / 32;
    const int n0 = w * (16 * NF);
    f32x4 acc[2][NF] = {};
#pragma unroll
    for (int ks = 0; ks < KS; ++ks) {
        const int kb = ks * 32 + hi * 8;
        s16x8 aw[NF], bh[2];
#pragma unroll
        for (int nf = 0; nf < NF; ++nf)
            aw[nf] = *(const s16x8*)(WT + (n0 + nf * 16 + lr) * K + kb);
#pragma unroll
        for (int mf = 0; mf < 2; ++mf) {
            int off = ((mf * 16 + lr) * (K * 2) + kb * 2) ^ ((lr & 7) << 4);
            bh[mf] = *(const s16x8*)((const char*)src + off);
        }
#pragma unroll
        for (int mf = 0; mf < 2; ++mf)
#pragma unroll
            for (int nf = 0; nf < NF; ++nf)
                acc[mf][nf] = __builtin_amdgcn_mfma_f32_16x16x32_bf16(aw[nf], bh[mf], acc[mf][nf], 0, 0, 0);
    }
    f32x4 bv[NF];
#pragma unroll
    for (int nf = 0; nf < NF; ++nf)
        bv[nf] = *(const f32x4*)(bias + n0 + nf * 16 + 4 * hi);
#pragma unroll
    for (int mf = 0; mf < 2; ++mf) {
        int m = mf * 16 + lr;
#pragma unroll
        for (int nf = 0; nf < NF; ++nf) {
            float v0 = acc[mf][nf][0] + bv[nf][0];
            float v1 = acc[mf][nf][1] + bv[nf][1];
            float v2 = acc[mf][nf][2] + bv[nf][2];
            float v3 = acc[mf][nf][3] + bv[nf][3];
            if (RELU) {
                v0 = fmaxf(v0, 0.f); v1 = fmaxf(v1, 0.f);
                v2 = fmaxf(v2, 0.f); v3 = fmaxf(v3, 0.f);
            }
            s16x4 pk = pack4(v0, v1, v2, v3);
            int off = (m * (N * 2) + (n0 + nf * 16 + 4 * hi) * 2) ^ ((m & 7) << 4);
            *(s16x4*)((char*)dst + off) = pk;
        }
    }
}

// ---------------------------------------------------------------------------
// Fused channel MLP: 64->128->256->256->32, all intermediates LDS-resident.
// ---------------------------------------------------------------------------
__global__ __launch_bounds__(256, 4)
void k_chanfused(const short* __restrict__ outb,
                 const short* __restrict__ Wc1T, const float* __restrict__ bc1,
                 const short* __restrict__ Wc2T, const float* __restrict__ bc2,
                 const short* __restrict__ Wc3T, const float* __restrict__ bc3,
                 const short* __restrict__ Wc4T, const float* __restrict__ bc4,
                 float* __restrict__ out)
{
    __shared__ short bufA[32 * 256];   // 16 KB
    __shared__ short bufB[32 * 256];   // 16 KB
    const int t = threadIdx.x, lane = t & 63, w = t >> 6;
    const int lr = lane & 15, hi = lane >> 4;
    const int bb = blockIdx.x >> 7;
    const int nm0 = (blockIdx.x & 127) * 32;

    // stage A0: [32 rows][64 c], row stride 128B, swizzled
    {
        int c = t & 63, rq = t >> 6;
        s16x8 v = *(const s16x8*)(outb + ((size_t)(bb * 64 + c)) * 4096 + nm0 + rq * 8);
#pragma unroll
        for (int q = 0; q < 8; ++q) {
            int row = rq * 8 + q;
            int off = (row * 128 + c * 2) ^ ((row & 7) << 4);
            *(short*)((char*)bufA + off) = v[q];
        }
    }
    __syncthreads();
    chan_layer< 64, 128, true>(bufA, Wc1T, bc1, bufB, w, lr, hi);
    __syncthreads();
    chan_layer<128, 256, true>(bufB, Wc2T, bc2, bufA, w, lr, hi);
    __syncthreads();
    chan_layer<256, 256, true>(bufA, Wc3T, bc3, bufB, w, lr, hi);
    __syncthreads();

    // c4: K=256, N=32, fp32 out.
    {
        const int wn = w & 1, wm = w >> 1;
        const int n0 = wn * 16;
        f32x4 acc = {};
#pragma unroll
        for (int ks = 0; ks < 8; ++ks) {
            const int kb = ks * 32 + hi * 8;
            s16x8 aw = *(const s16x8*)(Wc4T + (n0 + lr) * 256 + kb);
            int off = ((wm * 16 + lr) * 512 + kb * 2) ^ ((lr & 7) << 4);
            s16x8 bh = *(const s16x8*)((const char*)bufB + off);
            acc = __builtin_amdgcn_mfma_f32_16x16x32_bf16(aw, bh, acc, 0, 0, 0);
        }
        f32x4 bv = *(const f32x4*)(bc4 + n0 + 4 * hi);
        const int m = wm * 16 + lr;
#pragma unroll
        for (int q = 0; q < 4; ++q) {
            int n = n0 + 4 * hi + q;
            out[((size_t)(bb * 32 + n)) * 4096 + nm0 + m] = acc[q] + bv[q];
        }
    }
}

// ---------------------------------------------------------------------------
extern "C" void kernel_launch(void* const* d_in, const int* in_sizes, int n_in,
                              void* d_out, int out_size, void* d_ws, size_t ws_size,
                              hipStream_t stream)
{
    const float* x   = (const float*)d_in[0];
    const float* W1  = (const float*)d_in[1];
    const float* b1  = (const float*)d_in[2];
    const float* W2  = (const float*)d_in[3];
    const float* b2  = (const float*)d_in[4];
    const float* W3  = (const float*)d_in[5];
    const float* b3  = (const float*)d_in[6];
    const float* W4  = (const float*)d_in[7];
    const float* b4  = (const float*)d_in[8];
    const float* Wc1 = (const float*)d_in[9];
    const float* bc1 = (const float*)d_in[10];
    const float* Wc2 = (const float*)d_in[11];
    const float* bc2 = (const float*)d_in[12];
    const float* Wc3 = (const float*)d_in[13];
    const float* bc3 = (const float*)d_in[14];
    const float* Wc4 = (const float*)d_in[15];
    const float* bc4 = (const float*)d_in[16];
    float* out = (float*)d_out;

    char* ws = (char*)d_ws;
    // [0,2M) outb bf16 | [2M,8M) diagpart | [8M,...) weights
    short* outb     = (short*)(ws);
    float* diagpart = (float*)(ws + (2u << 20));

    size_t off = 8u << 20;
    short* W1T  = (short*)(ws + off); off += 4096 * 2;
    short* W2T  = (short*)(ws + off); off += 16384 * 2;
    short* W3T  = (short*)(ws + off); off += 16384 * 2;
    short* Wc1T = (short*)(ws + off); off += 8192 * 2;
    short* Wc2T = (short*)(ws + off); off += 32768 * 2;
    short* Wc3T = (short*)(ws + off); off += 65536 * 2;
    short* Wc4T = (short*)(ws + off); off += 8192 * 2;
    float* W4T  = (float*)(ws + off); off += 256 * 4;

    k_prep<<<256, 256, 0, stream>>>(W1, W2, W3, W4, Wc1, Wc2, Wc3, Wc4,
                                    W1T, W2T, W3T, W4T, Wc1T, Wc2T, Wc3T, Wc4T);
    k_phase1<<<16128, 256, 0, stream>>>(x, b1, W1T, W2T, b2, W3T, b3, W4T, b4,
                                        outb, diagpart);
    k_diag<<<256, 256, 0, stream>>>(diagpart, outb);
    k_chanfused<<<512, 256, 0, stream>>>(outb, Wc1T, bc1, Wc2T, bc2,
                                         Wc3T, bc3, Wc4T, bc4, out);
}